// Round 21
// baseline (117.772 us; speedup 1.0000x reference)
//
#include <hip/hip_runtime.h>
#include <hip/hip_bf16.h>
#include <math.h>

#define NRES 512
#define CS   384
#define CZ   128
#define NH   12
#define PW   1152   // packed projection width
#define JB   64     // j per flash block
#define NCH  8      // chunks = NRES/JB
#define PSTRIDE32 1040  // part chunk stride in u32 units
#define KS   6      // k_out K splits (2112 = 6*352)
#define KAW  352    // Kfull row width (11 * 32)

static constexpr float WL_F      = 0.57735026918962576f;   // sqrt(1/3)
static constexpr float HALF_WC_F = 0.11785113019775792f;   // 0.5*sqrt(2/(9*4))

typedef __attribute__((ext_vector_type(8))) short short8v;
typedef __attribute__((ext_vector_type(4))) float floatx4;

__device__ __forceinline__ ushort f2b(float f) {
    union { float f; uint u; } v; v.f = f;
    return (ushort)((v.u + 0x7FFFu + ((v.u >> 16) & 1u)) >> 16);
}
__device__ __forceinline__ float b2f(ushort b) {
    union { uint u; float f; } v; v.u = ((uint)b) << 16; return v.f;
}
__device__ __forceinline__ int ltb_addr(int h, int j) {
    return h * 64 + ((((j >> 3) ^ (h & 7))) << 3) + ((j >> 2) & 1) * 4 + (j & 3);
}

// ---------------------------------------------------------------------------
// Kernel 0: aux prep. blocks [0,512): Kfull + vp2 from P (per row);
// blocks [512,710): Wout -> WoutT16 transpose tiles; block 710: wbt16.
// ---------------------------------------------------------------------------
__global__ __launch_bounds__(256) void k_aux(
    const float* __restrict__ P, const float* __restrict__ Wb,
    const float* __restrict__ Wout,
    ushort* __restrict__ Kfull, ushort* __restrict__ vp2,
    ushort* __restrict__ wbt16, ushort* __restrict__ woT)
{
    __shared__ ushort tile[64][72];
    __shared__ float njs[NH];
    const int bx = blockIdx.x;
    const int tid = threadIdx.x;
    if (bx < 512) {
        const int j = bx;
        const float* prow = P + (size_t)j * PW;
        const float* kr  = prow + 192;
        const float* vr  = prow + 384;
        const float* kgr = prow + 720;
        const float* vgr = prow + 864;
        if (tid < NH) {
            float s = 0.f;
            #pragma unroll
            for (int e = 0; e < 12; ++e) { const float v = kgr[tid * 12 + e]; s += v * v; }
            njs[tid] = s;
        }
        __syncthreads();
        ushort* dst = Kfull + (size_t)j * KAW;
        for (int t = tid; t < KAW; t += 256) {
            float v;
            if (t < 192)       v = kr[t];
            else if (t < 336)  v = kgr[t - 192];
            else if (t < 348)  v = njs[t - 336];
            else if (t == 348) v = 1.0f;
            else               v = 0.f;
            dst[t] = f2b(v);
        }
        const int p = j >> 1, par = j & 1;
        for (int c = tid; c < 480; c += 256) {
            const float v = (c < 192) ? vr[c] : vgr[c - 192];
            vp2[((size_t)p * 480 + c) * 2 + par] = f2b(v);
        }
    } else if (bx < 710) {
        const int t = bx - 512;
        const int k0 = (t % 33) * 64, c0 = (t / 33) * 64;
        for (int idx = tid; idx < 4096; idx += 256) {
            const int r = idx >> 6, c = idx & 63;
            tile[r][c] = f2b(Wout[(size_t)(k0 + r) * 384 + c0 + c]);
        }
        __syncthreads();
        for (int idx = tid; idx < 4096; idx += 256) {
            const int c = idx >> 6, r = idx & 63;
            woT[(size_t)(c0 + c) * 2112 + k0 + r] = tile[r][c];
        }
    } else {
        for (int idx = tid; idx < 16 * 128; idx += 256) {
            const int h = idx >> 7, cc = idx & 127;
            wbt16[idx] = (h < NH) ? f2b(WL_F * Wb[(size_t)cc * NH + h]) : (ushort)0;
        }
    }
}

// ---------------------------------------------------------------------------
// Kernel 1: P[512][1152] = s @ [Wq|Wk|Wv|Wqp|Wkp|Wvp], rigid transform fused
// for cols >= 576. B-tiles read directly from source weights.
// ---------------------------------------------------------------------------
__global__ __launch_bounds__(256) void k_gemm(
    const float* __restrict__ s,
    const float* __restrict__ Wq, const float* __restrict__ Wk,
    const float* __restrict__ Wv, const float* __restrict__ Wqp,
    const float* __restrict__ Wkp, const float* __restrict__ Wvp,
    const float* __restrict__ rots, const float* __restrict__ trans,
    float* __restrict__ P)
{
    const int tid = threadIdx.x;
    const int tx = tid & 15, ty = tid >> 4;
    const int n0 = blockIdx.x * 48;
    const int m0 = blockIdx.y * 32;
    __shared__ float As[32][34];
    __shared__ float Bs[32][50];
    __shared__ float rot_lds[32][12];

    const float* Wsel; int W, base;
    if (n0 < 192)      { Wsel = Wq;  W = 192; base = 0;   }
    else if (n0 < 384) { Wsel = Wk;  W = 192; base = 192; }
    else if (n0 < 576) { Wsel = Wv;  W = 192; base = 384; }
    else if (n0 < 720) { Wsel = Wqp; W = 144; base = 576; }
    else if (n0 < 864) { Wsel = Wkp; W = 144; base = 720; }
    else               { Wsel = Wvp; W = 288; base = 864; }
    const int nb = n0 - base;

    if (n0 >= 576) {
        for (int idx = tid; idx < 32 * 12; idx += 256) {
            int r = idx / 12, q = idx % 12;
            rot_lds[r][q] = (q < 9) ? rots[(size_t)(m0 + r) * 9 + q]
                                    : trans[(size_t)(m0 + r) * 3 + q - 9];
        }
    }

    float acc[2][3];
    #pragma unroll
    for (int u = 0; u < 2; ++u)
        #pragma unroll
        for (int v = 0; v < 3; ++v) acc[u][v] = 0.f;

    for (int k0 = 0; k0 < CS; k0 += 32) {
        __syncthreads();
        #pragma unroll
        for (int l = 0; l < 4; ++l) {
            int idx = tid + l * 256;
            int kk = idx & 31, r = idx >> 5;
            As[kk][r] = s[(size_t)(m0 + r) * CS + k0 + kk];
        }
        #pragma unroll
        for (int l = 0; l < 6; ++l) {
            int idx = tid + l * 256;
            int kk = idx / 48, cc = idx % 48;
            Bs[kk][cc] = Wsel[(size_t)(k0 + kk) * W + nb + cc];
        }
        __syncthreads();
        #pragma unroll
        for (int kk = 0; kk < 32; ++kk) {
            const float2 a = *(const float2*)&As[kk][ty * 2];
            const float b0 = Bs[kk][tx * 3], b1 = Bs[kk][tx * 3 + 1], b2 = Bs[kk][tx * 3 + 2];
            acc[0][0] += a.x * b0; acc[0][1] += a.x * b1; acc[0][2] += a.x * b2;
            acc[1][0] += a.y * b0; acc[1][1] += a.y * b1; acc[1][2] += a.y * b2;
        }
    }

    #pragma unroll
    for (int u = 0; u < 2; ++u) {
        float v0 = acc[u][0], v1 = acc[u][1], v2 = acc[u][2];
        if (n0 >= 576) {
            const float* RT = rot_lds[ty * 2 + u];
            const float p0 = v0, p1 = v1, p2 = v2;
            v0 = RT[0] * p0 + RT[1] * p1 + RT[2] * p2 + RT[9];
            v1 = RT[3] * p0 + RT[4] * p1 + RT[5] * p2 + RT[10];
            v2 = RT[6] * p0 + RT[7] * p1 + RT[8] * p2 + RT[11];
        }
        float* dst = P + (size_t)(m0 + ty * 2 + u) * PW + n0 + tx * 3;
        dst[0] = v0; dst[1] = v1; dst[2] = v2;
    }
}

// ---------------------------------------------------------------------------
// Kernel 2: MFMA flash chunk. grid (512 i, 8 jc), 256 threads (4 waves).
// R16 base + in-register softmax: MFMA output lane layout (head n=lane&15,
// 4 j's per lane) lets wave stats be 2 shfl_xor (16,32); cross-wave via
// wstat[4][16] (one barrier); each lane rescales its e_w by exp(m_w-m) and
// writes 4 bf16 probs as one 8B LDS store to ltb. ltf eliminated; pm/ps
// direct to global; halfacc overlays dead BfT. 4 barriers.
// ---------------------------------------------------------------------------
__global__ __launch_bounds__(256, 4) void k_flash(
    const float* __restrict__ z, const ushort* __restrict__ wbt16,
    const float* __restrict__ gamma, const float* __restrict__ P,
    const ushort* __restrict__ Kfull, const ushort* __restrict__ vp2,
    uint* __restrict__ part)
{
    const int i   = blockIdx.x;
    const int jc  = blockIdx.y;
    const int j0  = jc * JB;
    const int tid = threadIdx.x;
    const int wid = tid >> 6, lane = tid & 63;

    __shared__ __align__(16) short zbT[128 * JB];    // 16384 B
    __shared__ __align__(16) char  uni[8448];        // BfT; later halfacc
    __shared__ __align__(16) short ltb[16 * 64];     // 2048 B
    __shared__ float2 wstat[4][16];                  // 512 B

    short*  BfT     = (short*)uni;                   // [12][352] (logits phase)
    float4* halfacc = (float4*)uni;                  // [240] (after bar2)

    uint* pb32   = part + ((size_t)i * NCH + jc) * PSTRIDE32;
    ushort* pb16 = (ushort*)pb32;
    float* pbf   = (float*)pb32;

    const int jb = wid * 16 + (lane & 15);           // this thread's j row
    const int ko = (lane >> 4) * 8;                  // channel octet base
    const int n  = lane & 15;

    // ---- phase A: z load (batched) -> A-frags in regs + zbT scatter; BfT build ----
    short8v af[4];
    {
        const float* za = z + ((size_t)i * NRES + j0 + jb) * CZ + ko;
        float4 fz[8];
        #pragma unroll
        for (int m = 0; m < 4; ++m) {
            fz[2 * m]     = *(const float4*)(za + m * 32);
            fz[2 * m + 1] = *(const float4*)(za + m * 32 + 4);
        }
        #pragma unroll
        for (int m = 0; m < 4; ++m) {
            const float4 f0 = fz[2 * m], f1 = fz[2 * m + 1];
            short8v a;
            a[0] = (short)f2b(f0.x); a[1] = (short)f2b(f0.y);
            a[2] = (short)f2b(f0.z); a[3] = (short)f2b(f0.w);
            a[4] = (short)f2b(f1.x); a[5] = (short)f2b(f1.y);
            a[6] = (short)f2b(f1.z); a[7] = (short)f2b(f1.w);
            af[m] = a;
            #pragma unroll
            for (int e = 0; e < 8; ++e) {
                const int c = ko + m * 32 + e;
                zbT[c * 64 + (((jb >> 3) ^ (c & 7)) * 8) + (jb & 7)] = a[e];
            }
        }
    }
    {
        const float* prow = P + (size_t)i * PW;
        for (int t = tid; t < 12 * 352; t += 256) {
            const int h = t / 352, k = t - h * 352;
            float v = 0.f;
            if (k < 192) {
                if ((k >> 4) == h) v = 0.25f * WL_F * prow[k];
            } else if (k < 336) {
                const int e = k - 192;
                if (e / 12 == h) v = 2.f * HALF_WC_F * WL_F * gamma[h] * prow[576 + e];
            } else if (k < 348) {
                if (k - 336 == h) v = -HALF_WC_F * WL_F * gamma[h];
            } else if (k == 348) {
                float ss = 0.f;
                #pragma unroll
                for (int e = 0; e < 12; ++e) {
                    const float x = prow[576 + h * 12 + e];
                    ss += x * x;
                }
                v = -HALF_WC_F * WL_F * gamma[h] * ss;
            }
            BfT[t] = (short)f2b(v);
        }
    }
    __syncthreads();   // bar1: zbT + BfT ready

    // ---- phase B: fused logits MFMA + wave-level softmax stats ----
    floatx4 lacc = {0.f, 0.f, 0.f, 0.f};
    float ew0, ew1, ew2, ew3, wm;
    {
        const int nb2 = (n < NH) ? n : 0;            // clamp pad cols
        const ushort* arow = Kfull + (size_t)(j0 + jb) * KAW + ko;
        const short*  brow = &BfT[nb2 * 352 + ko];
        const ushort* wrow = wbt16 + n * 128 + ko;
        short8v kf[11], wv[4];
        #pragma unroll
        for (int st = 0; st < 11; ++st) kf[st] = *(const short8v*)(arow + st * 32);
        #pragma unroll
        for (int st = 0; st < 4; ++st)  wv[st] = *(const short8v*)(wrow + st * 32);
        #pragma unroll
        for (int st = 0; st < 11; ++st) {
            const short8v b = *(const short8v*)(brow + st * 32);
            lacc = __builtin_amdgcn_mfma_f32_16x16x32_bf16(kf[st], b, lacc, 0, 0, 0);
        }
        #pragma unroll
        for (int st = 0; st < 4; ++st)
            lacc = __builtin_amdgcn_mfma_f32_16x16x32_bf16(af[st], wv[st], lacc, 0, 0, 0);

        // wave stats over this wave's 16 j for head n (lanes n, n+16, n+32, n+48)
        wm = fmaxf(fmaxf(lacc[0], lacc[1]), fmaxf(lacc[2], lacc[3]));
        wm = fmaxf(wm, __shfl_xor(wm, 16));
        wm = fmaxf(wm, __shfl_xor(wm, 32));
        ew0 = __expf(lacc[0] - wm); ew1 = __expf(lacc[1] - wm);
        ew2 = __expf(lacc[2] - wm); ew3 = __expf(lacc[3] - wm);
        float wsum = ew0 + ew1 + ew2 + ew3;
        wsum += __shfl_xor(wsum, 16);
        wsum += __shfl_xor(wsum, 32);
        if ((lane >> 4) == 0) wstat[wid][n] = make_float2(wm, wsum);
    }
    __syncthreads();   // bar2: stats ready; BfT reads done (halfacc region free)

    // ---- phase C: global stats, rescale, bf16 prob write (one 8B store) ----
    {
        const float2 s0 = wstat[0][n], s1 = wstat[1][n];
        const float2 s2 = wstat[2][n], s3 = wstat[3][n];
        const float m = fmaxf(fmaxf(s0.x, s1.x), fmaxf(s2.x, s3.x));
        uint2 w = {0u, 0u};
        if (n < NH) {
            const float sc = __expf(wm - m);
            const float e0 = ew0 * sc, e1 = ew1 * sc, e2 = ew2 * sc, e3 = ew3 * sc;
            w.x = (uint)f2b(e0) | ((uint)f2b(e1) << 16);
            w.y = (uint)f2b(e2) | ((uint)f2b(e3) << 16);
        }
        const int j0b = wid * 16 + (lane >> 4) * 4;
        *(uint2*)&ltb[n * 64 + (((j0b >> 3) ^ (n & 7)) << 3) + ((j0b >> 2) & 1) * 4] = w;
        if (tid < NH) {
            const float S = s0.y * __expf(s0.x - m) + s1.y * __expf(s1.x - m) +
                            s2.y * __expf(s2.x - m) + s3.y * __expf(s3.x - m);
            pbf[1008 + tid] = m;
            pbf[1020 + tid] = S;
        }
    }
    __syncthreads();   // bar3: ltb ready

    // ---- phase D: o_hat MFMA — all 4 waves, 2 N-tiles each ----
    {
        const int hrow = lane & 15;
        const int u0 = (lane >> 4), u1 = u0 + 4;
        const short8v a0 = *(const short8v*)&ltb[hrow * 64 + ((u0 ^ (hrow & 7)) * 8)];
        const short8v a1 = *(const short8v*)&ltb[hrow * 64 + ((u1 ^ (hrow & 7)) * 8)];
        #pragma unroll
        for (int t = 0; t < 2; ++t) {
            const int d = (wid * 2 + t) * 16 + (lane & 15);
            const short8v b0 = *(const short8v*)&zbT[d * 64 + ((u0 ^ (d & 7)) * 8)];
            const short8v b1 = *(const short8v*)&zbT[d * 64 + ((u1 ^ (d & 7)) * 8)];
            floatx4 acc = {0.f, 0.f, 0.f, 0.f};
            acc = __builtin_amdgcn_mfma_f32_16x16x32_bf16(a0, b0, acc, 0, 0, 0);
            acc = __builtin_amdgcn_mfma_f32_16x16x32_bf16(a1, b1, acc, 0, 0, 0);
            #pragma unroll
            for (int r = 0; r < 4; ++r) {
                const int h = u0 * 4 + r;
                if (h < NH) pb16[h * 128 + d] = f2b(acc[r]);
            }
        }
    }

    // ---- phase E: o / o_hp — vp2 packed, probs read from ltb (bf16) ----
    {
        if (tid < 240) {
            const int half = tid / 120, col = tid % 120;
            const int h = (col < 48) ? (col >> 2) : ((col - 48) / 6);
            const ushort* vb = vp2 + ((size_t)((j0 >> 1) + half * 16) * 480 + col * 4) * 2;
            float ax = 0.f, ay = 0.f, az = 0.f, aw = 0.f;
            #pragma unroll
            for (int b = 0; b < 2; ++b) {
                uint4 raw[8];
                #pragma unroll
                for (int t = 0; t < 8; ++t)
                    raw[t] = *(const uint4*)(vb + (size_t)(b * 8 + t) * 960);
                #pragma unroll
                for (int t = 0; t < 8; ++t) {
                    const int jj = half * 32 + 2 * (b * 8 + t);
                    const float e0 = b2f((ushort)ltb[ltb_addr(h, jj)]);
                    const float e1 = b2f((ushort)ltb[ltb_addr(h, jj + 1)]);
                    ax += e0 * b2f((ushort)raw[t].x) + e1 * b2f((ushort)(raw[t].x >> 16));
                    ay += e0 * b2f((ushort)raw[t].y) + e1 * b2f((ushort)(raw[t].y >> 16));
                    az += e0 * b2f((ushort)raw[t].z) + e1 * b2f((ushort)(raw[t].z >> 16));
                    aw += e0 * b2f((ushort)raw[t].w) + e1 * b2f((ushort)(raw[t].w >> 16));
                }
            }
            halfacc[tid] = make_float4(ax, ay, az, aw);
        }
        __syncthreads();   // bar4: halfacc ready
        if (tid < 120) {
            const float4 s0 = halfacc[tid], s1 = halfacc[tid + 120];
            const int off16 = (tid < 48) ? 1536 + tid * 4 : 1728 + (tid - 48) * 4;
            uint* dst = (uint*)&pb16[off16];
            dst[0] = (uint)f2b(s0.x + s1.x) | ((uint)f2b(s0.y + s1.y) << 16);
            dst[1] = (uint)f2b(s0.z + s1.z) | ((uint)f2b(s0.w + s1.w) << 16);
        }
    }
}

// ---------------------------------------------------------------------------
// Kernel 3: combine 8 chunks -> cat16 row (bf16). grid 512, 256 threads.
// ---------------------------------------------------------------------------
__global__ __launch_bounds__(256) void k_combine(
    const uint* __restrict__ part, const float* __restrict__ rots,
    const float* __restrict__ trans, ushort* __restrict__ cat16)
{
    const int i   = blockIdx.x;
    const int tid = threadIdx.x;
    __shared__ float wgt[NCH][NH];
    __shared__ float ohp[288];

    const uint* base = part + (size_t)i * NCH * PSTRIDE32;
    if (tid < NH) {
        const int h = tid;
        float mm[NCH];
        float M = -1e30f;
        #pragma unroll
        for (int c = 0; c < NCH; ++c) {
            mm[c] = ((const float*)(base + c * PSTRIDE32))[1008 + h];
            M = fmaxf(M, mm[c]);
        }
        float S = 0.f;
        #pragma unroll
        for (int c = 0; c < NCH; ++c) {
            const float w = __expf(mm[c] - M);
            S += w * ((const float*)(base + c * PSTRIDE32))[1020 + h];
            wgt[c][h] = w;
        }
        const float inv = 1.0f / S;
        #pragma unroll
        for (int c = 0; c < NCH; ++c) wgt[c][h] *= inv;
    }
    __syncthreads();

    ushort* crow = cat16 + (size_t)i * 2112;
    uint*   crowu = (uint*)crow;
    if (tid < 192) {
        const int h = tid >> 4;
        float v[8];
        #pragma unroll
        for (int e = 0; e < 8; ++e) v[e] = 0.f;
        #pragma unroll
        for (int c = 0; c < NCH; ++c) {
            const uint4 u = *(const uint4*)&base[c * PSTRIDE32 + tid * 4];
            const float w = wgt[c][h];
            v[0] += b2f((ushort)u.x) * w; v[1] += b2f((ushort)(u.x >> 16)) * w;
            v[2] += b2f((ushort)u.y) * w; v[3] += b2f((ushort)(u.y >> 16)) * w;
            v[4] += b2f((ushort)u.z) * w; v[5] += b2f((ushort)(u.z >> 16)) * w;
            v[6] += b2f((ushort)u.w) * w; v[7] += b2f((ushort)(u.w >> 16)) * w;
        }
        uint4 o;
        o.x = (uint)f2b(v[0]) | ((uint)f2b(v[1]) << 16);
        o.y = (uint)f2b(v[2]) | ((uint)f2b(v[3]) << 16);
        o.z = (uint)f2b(v[4]) | ((uint)f2b(v[5]) << 16);
        o.w = (uint)f2b(v[6]) | ((uint)f2b(v[7]) << 16);
        *(uint4*)&crowu[tid * 4] = o;
    }
    if (tid < 96) {
        const int h = tid >> 3;
        float v0 = 0.f, v1 = 0.f;
        #pragma unroll
        for (int c = 0; c < NCH; ++c) {
            const uint u = base[c * PSTRIDE32 + 768 + tid];
            const float w = wgt[c][h];
            v0 += b2f((ushort)u) * w;
            v1 += b2f((ushort)(u >> 16)) * w;
        }
        crowu[768 + tid] = (uint)f2b(v0) | ((uint)f2b(v1) << 16);
    }
    if (tid < 144) {
        const int h = tid / 12;
        float v0 = 0.f, v1 = 0.f;
        #pragma unroll
        for (int c = 0; c < NCH; ++c) {
            const uint u = base[c * PSTRIDE32 + 864 + tid];
            const float w = wgt[c][h];
            v0 += b2f((ushort)u) * w;
            v1 += b2f((ushort)(u >> 16)) * w;
        }
        ohp[tid * 2] = v0; ohp[tid * 2 + 1] = v1;
    }
    __syncthreads();

    if (tid < 96) {
        const int h = tid >> 3, p = tid & 7;
        float R[9];
        #pragma unroll
        for (int k = 0; k < 9; ++k) R[k] = rots[(size_t)i * 9 + k];
        const float g0 = ohp[h * 24 + p * 3 + 0] - trans[(size_t)i * 3 + 0];
        const float g1 = ohp[h * 24 + p * 3 + 1] - trans[(size_t)i * 3 + 1];
        const float g2 = ohp[h * 24 + p * 3 + 2] - trans[(size_t)i * 3 + 2];
        const float oy0 = R[0] * g0 + R[3] * g1 + R[6] * g2;
        const float oy1 = R[1] * g0 + R[4] * g1 + R[7] * g2;
        const float oy2 = R[2] * g0 + R[5] * g1 + R[8] * g2;
        crow[1728 + h * 24 + p * 3 + 0] = f2b(oy0);
        crow[1728 + h * 24 + p * 3 + 1] = f2b(oy1);
        crow[1728 + h * 24 + p * 3 + 2] = f2b(oy2);
        crow[2016 + h * 8 + p] = f2b(sqrtf(oy0 * oy0 + oy1 * oy1 + oy2 * oy2));
    }
}

// ---------------------------------------------------------------------------
// Kernel 4: out-proj MFMA. grid (16 m, 12 n, 6 k). 4 waves = 2x2 16x16 tiles.
// ---------------------------------------------------------------------------
__global__ __launch_bounds__(256) void k_out(
    const ushort* __restrict__ cat16, const ushort* __restrict__ woT,
    float* __restrict__ opart)
{
    const int tid = threadIdx.x;
    const int wid = tid >> 6, lane = tid & 63;
    const int wm = wid >> 1, wn = wid & 1;
    const int i0 = blockIdx.x * 32 + wm * 16;
    const int c0 = blockIdx.y * 32 + wn * 16;
    const int k0 = blockIdx.z * 352;
    const ushort* arow = cat16 + (size_t)(i0 + (lane & 15)) * 2112 + k0 + (lane >> 4) * 8;
    const ushort* brow = woT   + (size_t)(c0 + (lane & 15)) * 2112 + k0 + (lane >> 4) * 8;
    floatx4 acc = {0.f, 0.f, 0.f, 0.f};
    #pragma unroll
    for (int st = 0; st < 11; ++st) {
        const short8v a = *(const short8v*)(arow + st * 32);
        const short8v b = *(const short8v*)(brow + st * 32);
        acc = __builtin_amdgcn_mfma_f32_16x16x32_bf16(a, b, acc, 0, 0, 0);
    }
    float* ob = opart + (size_t)blockIdx.z * 512 * 384;
    #pragma unroll
    for (int r = 0; r < 4; ++r) {
        const int i = i0 + (lane >> 4) * 4 + r;
        ob[(size_t)i * 384 + c0 + (lane & 15)] = acc[r];
    }
}

// Kernel 5: reduce 6 k-partials + bias.
__global__ __launch_bounds__(256) void k_outred(
    const float* __restrict__ opart, const float* __restrict__ bout,
    float* __restrict__ out)
{
    const int e4 = blockIdx.x * 256 + threadIdx.x;
    const float4* p = (const float4*)opart;
    const float4 b = ((const float4*)bout)[e4 % 96];
    float4 r = b;
    #pragma unroll
    for (int k = 0; k < KS; ++k) {
        const float4 v = p[e4 + k * 49152];
        r.x += v.x; r.y += v.y; r.z += v.z; r.w += v.w;
    }
    ((float4*)out)[e4] = r;
}

// ---------------------------------------------------------------------------
extern "C" void kernel_launch(void* const* d_in, const int* in_sizes, int n_in,
                              void* d_out, int out_size, void* d_ws, size_t ws_size,
                              hipStream_t stream)
{
    const float* s_i   = (const float*)d_in[0];
    const float* z_ij  = (const float*)d_in[1];
    const float* rots  = (const float*)d_in[2];
    const float* trans = (const float*)d_in[3];
    const float* Wq    = (const float*)d_in[4];
    const float* Wk    = (const float*)d_in[5];
    const float* Wv    = (const float*)d_in[6];
    const float* Wqp   = (const float*)d_in[7];
    const float* Wkp   = (const float*)d_in[8];
    const float* Wvp   = (const float*)d_in[9];
    const float* Wb    = (const float*)d_in[10];
    const float* gamma = (const float*)d_in[11];
    const float* Wout  = (const float*)d_in[12];
    const float* bout  = (const float*)d_in[13];
    float* ws = (float*)d_ws;
    float*  P     = ws;                          // 589824 f
    uint*   part  = (uint*)(P + 589824);         // 512*8*1040 u32 (17 MB)
    float*  opart = (float*)part;                // aliased (part consumed by
                                                 // k_combine before k_out writes)
    ushort* cat16 = (ushort*)(part + (size_t)512 * NCH * PSTRIDE32);  // 1081344 u16
    ushort* wbt16 = cat16 + 1081344;             // 2048 u16
    ushort* kfull = wbt16 + 2048;                // 512*352 u16
    ushort* woT   = kfull + 512 * KAW;           // 384*2112 u16
    ushort* vp2   = woT + (size_t)384 * 2112;    // 256*480*2 u16
    float*  out   = (float*)d_out;

    hipLaunchKernelGGL(k_gemm, dim3(24, 16), dim3(256), 0, stream,
                       s_i, Wq, Wk, Wv, Wqp, Wkp, Wvp, rots, trans, P);
    hipLaunchKernelGGL(k_aux, dim3(711), dim3(256), 0, stream,
                       P, Wb, Wout, kfull, vp2, wbt16, woT);
    hipLaunchKernelGGL(k_flash, dim3(512, NCH), dim3(256), 0, stream,
                       z_ij, wbt16, gamma, P, kfull, vp2, part);
    hipLaunchKernelGGL(k_combine, dim3(512), dim3(256), 0, stream,
                       part, rots, trans, cat16);
    hipLaunchKernelGGL(k_out, dim3(16, 12, KS), dim3(256), 0, stream,
                       cat16, woT, opart);
    hipLaunchKernelGGL(k_outred, dim3(192), dim3(256), 0, stream,
                       opart, bout, out);
}

// Round 22
// 116.026 us; speedup vs baseline: 1.0151x; 1.0151x over previous
//
#include <hip/hip_runtime.h>
#include <hip/hip_bf16.h>
#include <math.h>

#define NRES 512
#define CS   384
#define CZ   128
#define NH   12
#define PW   1152   // packed projection width
#define JB   64     // j per flash block
#define NCH  8      // chunks = NRES/JB
#define PSTRIDE32 1040  // part chunk stride in u32 units
#define KS   6      // k_out K splits (2112 = 6*352)
#define KAW  352    // Kfull row width (11 * 32)

static constexpr float WL_F      = 0.57735026918962576f;   // sqrt(1/3)
static constexpr float HALF_WC_F = 0.11785113019775792f;   // 0.5*sqrt(2/(9*4))

typedef __attribute__((ext_vector_type(8))) short short8v;
typedef __attribute__((ext_vector_type(4))) float floatx4;

__device__ __forceinline__ ushort f2b(float f) {
    union { float f; uint u; } v; v.f = f;
    return (ushort)((v.u + 0x7FFFu + ((v.u >> 16) & 1u)) >> 16);
}
__device__ __forceinline__ float b2f(ushort b) {
    union { uint u; float f; } v; v.u = ((uint)b) << 16; return v.f;
}

// ---------------------------------------------------------------------------
// Kernel 0: aux prep. blocks [0,512): Kfull + vp2 from P (per row);
// blocks [512,710): Wout -> WoutT16 transpose tiles; block 710: wbt16.
// ---------------------------------------------------------------------------
__global__ __launch_bounds__(256) void k_aux(
    const float* __restrict__ P, const float* __restrict__ Wb,
    const float* __restrict__ Wout,
    ushort* __restrict__ Kfull, ushort* __restrict__ vp2,
    ushort* __restrict__ wbt16, ushort* __restrict__ woT)
{
    __shared__ ushort tile[64][72];
    __shared__ float njs[NH];
    const int bx = blockIdx.x;
    const int tid = threadIdx.x;
    if (bx < 512) {
        const int j = bx;
        const float* prow = P + (size_t)j * PW;
        const float* kr  = prow + 192;
        const float* vr  = prow + 384;
        const float* kgr = prow + 720;
        const float* vgr = prow + 864;
        if (tid < NH) {
            float s = 0.f;
            #pragma unroll
            for (int e = 0; e < 12; ++e) { const float v = kgr[tid * 12 + e]; s += v * v; }
            njs[tid] = s;
        }
        __syncthreads();
        ushort* dst = Kfull + (size_t)j * KAW;
        for (int t = tid; t < KAW; t += 256) {
            float v;
            if (t < 192)       v = kr[t];
            else if (t < 336)  v = kgr[t - 192];
            else if (t < 348)  v = njs[t - 336];
            else if (t == 348) v = 1.0f;
            else               v = 0.f;
            dst[t] = f2b(v);
        }
        const int p = j >> 1, par = j & 1;
        for (int c = tid; c < 480; c += 256) {
            const float v = (c < 192) ? vr[c] : vgr[c - 192];
            vp2[((size_t)p * 480 + c) * 2 + par] = f2b(v);
        }
    } else if (bx < 710) {
        const int t = bx - 512;
        const int k0 = (t % 33) * 64, c0 = (t / 33) * 64;
        for (int idx = tid; idx < 4096; idx += 256) {
            const int r = idx >> 6, c = idx & 63;
            tile[r][c] = f2b(Wout[(size_t)(k0 + r) * 384 + c0 + c]);
        }
        __syncthreads();
        for (int idx = tid; idx < 4096; idx += 256) {
            const int c = idx >> 6, r = idx & 63;
            woT[(size_t)(c0 + c) * 2112 + k0 + r] = tile[r][c];
        }
    } else {
        for (int idx = tid; idx < 16 * 128; idx += 256) {
            const int h = idx >> 7, cc = idx & 127;
            wbt16[idx] = (h < NH) ? f2b(WL_F * Wb[(size_t)cc * NH + h]) : (ushort)0;
        }
    }
}

// ---------------------------------------------------------------------------
// Kernel 1: P[512][1152] = s @ [Wq|Wk|Wv|Wqp|Wkp|Wvp], rigid transform fused
// for cols >= 576. B-tiles read directly from source weights.
// ---------------------------------------------------------------------------
__global__ __launch_bounds__(256) void k_gemm(
    const float* __restrict__ s,
    const float* __restrict__ Wq, const float* __restrict__ Wk,
    const float* __restrict__ Wv, const float* __restrict__ Wqp,
    const float* __restrict__ Wkp, const float* __restrict__ Wvp,
    const float* __restrict__ rots, const float* __restrict__ trans,
    float* __restrict__ P)
{
    const int tid = threadIdx.x;
    const int tx = tid & 15, ty = tid >> 4;
    const int n0 = blockIdx.x * 48;
    const int m0 = blockIdx.y * 32;
    __shared__ float As[32][34];
    __shared__ float Bs[32][50];
    __shared__ float rot_lds[32][12];

    const float* Wsel; int W, base;
    if (n0 < 192)      { Wsel = Wq;  W = 192; base = 0;   }
    else if (n0 < 384) { Wsel = Wk;  W = 192; base = 192; }
    else if (n0 < 576) { Wsel = Wv;  W = 192; base = 384; }
    else if (n0 < 720) { Wsel = Wqp; W = 144; base = 576; }
    else if (n0 < 864) { Wsel = Wkp; W = 144; base = 720; }
    else               { Wsel = Wvp; W = 288; base = 864; }
    const int nb = n0 - base;

    if (n0 >= 576) {
        for (int idx = tid; idx < 32 * 12; idx += 256) {
            int r = idx / 12, q = idx % 12;
            rot_lds[r][q] = (q < 9) ? rots[(size_t)(m0 + r) * 9 + q]
                                    : trans[(size_t)(m0 + r) * 3 + q - 9];
        }
    }

    float acc[2][3];
    #pragma unroll
    for (int u = 0; u < 2; ++u)
        #pragma unroll
        for (int v = 0; v < 3; ++v) acc[u][v] = 0.f;

    for (int k0 = 0; k0 < CS; k0 += 32) {
        __syncthreads();
        #pragma unroll
        for (int l = 0; l < 4; ++l) {
            int idx = tid + l * 256;
            int kk = idx & 31, r = idx >> 5;
            As[kk][r] = s[(size_t)(m0 + r) * CS + k0 + kk];
        }
        #pragma unroll
        for (int l = 0; l < 6; ++l) {
            int idx = tid + l * 256;
            int kk = idx / 48, cc = idx % 48;
            Bs[kk][cc] = Wsel[(size_t)(k0 + kk) * W + nb + cc];
        }
        __syncthreads();
        #pragma unroll
        for (int kk = 0; kk < 32; ++kk) {
            const float2 a = *(const float2*)&As[kk][ty * 2];
            const float b0 = Bs[kk][tx * 3], b1 = Bs[kk][tx * 3 + 1], b2 = Bs[kk][tx * 3 + 2];
            acc[0][0] += a.x * b0; acc[0][1] += a.x * b1; acc[0][2] += a.x * b2;
            acc[1][0] += a.y * b0; acc[1][1] += a.y * b1; acc[1][2] += a.y * b2;
        }
    }

    #pragma unroll
    for (int u = 0; u < 2; ++u) {
        float v0 = acc[u][0], v1 = acc[u][1], v2 = acc[u][2];
        if (n0 >= 576) {
            const float* RT = rot_lds[ty * 2 + u];
            const float p0 = v0, p1 = v1, p2 = v2;
            v0 = RT[0] * p0 + RT[1] * p1 + RT[2] * p2 + RT[9];
            v1 = RT[3] * p0 + RT[4] * p1 + RT[5] * p2 + RT[10];
            v2 = RT[6] * p0 + RT[7] * p1 + RT[8] * p2 + RT[11];
        }
        float* dst = P + (size_t)(m0 + ty * 2 + u) * PW + n0 + tx * 3;
        dst[0] = v0; dst[1] = v1; dst[2] = v2;
    }
}

// ---------------------------------------------------------------------------
// Kernel 2: MFMA flash chunk. grid (512 i, 8 jc), 256 threads (4 waves).
// R16-proven: z once (batched), LDS BfT build, 15-step logit MFMA, softmax,
// o_hat MFMA, vp2 phase E (2 batches of 8 loads).
// ---------------------------------------------------------------------------
__global__ __launch_bounds__(256, 4) void k_flash(
    const float* __restrict__ z, const ushort* __restrict__ wbt16,
    const float* __restrict__ gamma, const float* __restrict__ P,
    const ushort* __restrict__ Kfull, const ushort* __restrict__ vp2,
    uint* __restrict__ part)
{
    const int i   = blockIdx.x;
    const int jc  = blockIdx.y;
    const int j0  = jc * JB;
    const int tid = threadIdx.x;
    const int wid = tid >> 6, lane = tid & 63;

    __shared__ __align__(16) short zbT[128 * JB];    // 16384 B
    __shared__ __align__(16) char  uni[10240];       // BfT | {ltf, ltb, halfacc}
    __shared__ float pm[NH], ps[NH];

    short*  BfT     = (short*)uni;                   // [12][352] (logits phase)
    float*  ltf     = (float*)uni;                   // [16][68]  (after)
    short*  ltb     = (short*)(uni + 4352);          // [16][64]
    float4* halfacc = (float4*)(uni + 6400);         // [240]

    uint* pb32   = part + ((size_t)i * NCH + jc) * PSTRIDE32;
    ushort* pb16 = (ushort*)pb32;
    float* pbf   = (float*)pb32;

    const int jb = wid * 16 + (lane & 15);           // this thread's j row
    const int ko = (lane >> 4) * 8;                  // channel octet base

    // ---- phase A: z load (batched) -> A-frags in regs + zbT scatter; BfT build ----
    short8v af[4];
    {
        const float* za = z + ((size_t)i * NRES + j0 + jb) * CZ + ko;
        float4 fz[8];
        #pragma unroll
        for (int m = 0; m < 4; ++m) {
            fz[2 * m]     = *(const float4*)(za + m * 32);
            fz[2 * m + 1] = *(const float4*)(za + m * 32 + 4);
        }
        #pragma unroll
        for (int m = 0; m < 4; ++m) {
            const float4 f0 = fz[2 * m], f1 = fz[2 * m + 1];
            short8v a;
            a[0] = (short)f2b(f0.x); a[1] = (short)f2b(f0.y);
            a[2] = (short)f2b(f0.z); a[3] = (short)f2b(f0.w);
            a[4] = (short)f2b(f1.x); a[5] = (short)f2b(f1.y);
            a[6] = (short)f2b(f1.z); a[7] = (short)f2b(f1.w);
            af[m] = a;
            #pragma unroll
            for (int e = 0; e < 8; ++e) {
                const int c = ko + m * 32 + e;
                zbT[c * 64 + (((jb >> 3) ^ (c & 7)) * 8) + (jb & 7)] = a[e];
            }
        }
    }
    {
        const float* prow = P + (size_t)i * PW;
        for (int t = tid; t < 12 * 352; t += 256) {
            const int h = t / 352, k = t - h * 352;
            float v = 0.f;
            if (k < 192) {
                if ((k >> 4) == h) v = 0.25f * WL_F * prow[k];
            } else if (k < 336) {
                const int e = k - 192;
                if (e / 12 == h) v = 2.f * HALF_WC_F * WL_F * gamma[h] * prow[576 + e];
            } else if (k < 348) {
                if (k - 336 == h) v = -HALF_WC_F * WL_F * gamma[h];
            } else if (k == 348) {
                float ss = 0.f;
                #pragma unroll
                for (int e = 0; e < 12; ++e) {
                    const float x = prow[576 + h * 12 + e];
                    ss += x * x;
                }
                v = -HALF_WC_F * WL_F * gamma[h] * ss;
            }
            BfT[t] = (short)f2b(v);
        }
    }
    __syncthreads();

    // ---- phase B: fused logits MFMA — prefetch all global frags, then chain ----
    floatx4 lacc = {0.f, 0.f, 0.f, 0.f};
    {
        const int n  = lane & 15;
        const int nb = (n < NH) ? n : 0;             // clamp garbage cols
        const ushort* arow = Kfull + (size_t)(j0 + jb) * KAW + ko;
        const short*  brow = &BfT[nb * 352 + ko];
        const ushort* wrow = wbt16 + n * 128 + ko;
        short8v kf[11], wv[4];
        #pragma unroll
        for (int st = 0; st < 11; ++st) kf[st] = *(const short8v*)(arow + st * 32);
        #pragma unroll
        for (int st = 0; st < 4; ++st)  wv[st] = *(const short8v*)(wrow + st * 32);
        #pragma unroll
        for (int st = 0; st < 11; ++st) {
            const short8v b = *(const short8v*)(brow + st * 32);
            lacc = __builtin_amdgcn_mfma_f32_16x16x32_bf16(kf[st], b, lacc, 0, 0, 0);
        }
        #pragma unroll
        for (int st = 0; st < 4; ++st)
            lacc = __builtin_amdgcn_mfma_f32_16x16x32_bf16(af[st], wv[st], lacc, 0, 0, 0);
    }
    __syncthreads();   // all waves done reading BfT
    {
        const int n = lane & 15;
        #pragma unroll
        for (int r = 0; r < 4; ++r)
            ltf[n * 68 + wid * 16 + (lane >> 4) * 4 + r] = lacc[r];
    }
    __syncthreads();

    // ---- phase C: chunk softmax (16 lanes/head) ----
    if (tid < 192) {
        const int h = tid >> 4, s = tid & 15;
        float4 v = *(const float4*)&ltf[h * 68 + s * 4];
        float m = fmaxf(fmaxf(v.x, v.y), fmaxf(v.z, v.w));
        #pragma unroll
        for (int o = 1; o < 16; o <<= 1) m = fmaxf(m, __shfl_xor(m, o));
        float4 e;
        e.x = __expf(v.x - m); e.y = __expf(v.y - m);
        e.z = __expf(v.z - m); e.w = __expf(v.w - m);
        float sum = e.x + e.y + e.z + e.w;
        #pragma unroll
        for (int o = 1; o < 16; o <<= 1) sum += __shfl_xor(sum, o);
        *(float4*)&ltf[h * 68 + s * 4] = e;
        const uint lo = (uint)f2b(e.x) | ((uint)f2b(e.y) << 16);
        const uint hi = (uint)f2b(e.z) | ((uint)f2b(e.w) << 16);
        uint* dst = (uint*)&ltb[h * 64 + (((s >> 1) ^ (h & 7)) * 8) + (s & 1) * 4];
        dst[0] = lo; dst[1] = hi;
        if (s == 0) { pm[h] = m; ps[h] = sum; }
    } else {
        const int tt = tid - 192;
        uint* dst = (uint*)&ltb[(12 + (tt >> 4)) * 64 + (tt & 15) * 4];
        dst[0] = 0u; dst[1] = 0u;
    }
    __syncthreads();

    // ---- phase D: o_hat MFMA — all 4 waves, 2 N-tiles each ----
    {
        const int hrow = lane & 15;
        const int u0 = (lane >> 4), u1 = u0 + 4;
        const short8v a0 = *(const short8v*)&ltb[hrow * 64 + ((u0 ^ (hrow & 7)) * 8)];
        const short8v a1 = *(const short8v*)&ltb[hrow * 64 + ((u1 ^ (hrow & 7)) * 8)];
        #pragma unroll
        for (int t = 0; t < 2; ++t) {
            const int d = (wid * 2 + t) * 16 + (lane & 15);
            const short8v b0 = *(const short8v*)&zbT[d * 64 + ((u0 ^ (d & 7)) * 8)];
            const short8v b1 = *(const short8v*)&zbT[d * 64 + ((u1 ^ (d & 7)) * 8)];
            floatx4 acc = {0.f, 0.f, 0.f, 0.f};
            acc = __builtin_amdgcn_mfma_f32_16x16x32_bf16(a0, b0, acc, 0, 0, 0);
            acc = __builtin_amdgcn_mfma_f32_16x16x32_bf16(a1, b1, acc, 0, 0, 0);
            #pragma unroll
            for (int r = 0; r < 4; ++r) {
                const int h = u0 * 4 + r;
                if (h < NH) pb16[h * 128 + d] = f2b(acc[r]);
            }
        }
    }

    // ---- phase E: o / o_hp — 240 slots, vp2 packed, 2 batches of 8 loads ----
    {
        if (tid < 240) {
            const int half = tid / 120, col = tid % 120;
            const int h = (col < 48) ? (col >> 2) : ((col - 48) / 6);
            const ushort* vb = vp2 + ((size_t)((j0 >> 1) + half * 16) * 480 + col * 4) * 2;
            const float* er = &ltf[h * 68 + half * 32];
            float ax = 0.f, ay = 0.f, az = 0.f, aw = 0.f;
            #pragma unroll
            for (int b = 0; b < 2; ++b) {
                uint4 raw[8];
                #pragma unroll
                for (int t = 0; t < 8; ++t)
                    raw[t] = *(const uint4*)(vb + (size_t)(b * 8 + t) * 960);
                #pragma unroll
                for (int t = 0; t < 8; ++t) {
                    const float e0 = er[2 * (b * 8 + t)], e1 = er[2 * (b * 8 + t) + 1];
                    ax += e0 * b2f((ushort)raw[t].x) + e1 * b2f((ushort)(raw[t].x >> 16));
                    ay += e0 * b2f((ushort)raw[t].y) + e1 * b2f((ushort)(raw[t].y >> 16));
                    az += e0 * b2f((ushort)raw[t].z) + e1 * b2f((ushort)(raw[t].z >> 16));
                    aw += e0 * b2f((ushort)raw[t].w) + e1 * b2f((ushort)(raw[t].w >> 16));
                }
            }
            halfacc[tid] = make_float4(ax, ay, az, aw);
        }
        __syncthreads();
        if (tid < 120) {
            const float4 s0 = halfacc[tid], s1 = halfacc[tid + 120];
            const int off16 = (tid < 48) ? 1536 + tid * 4 : 1728 + (tid - 48) * 4;
            uint* dst = (uint*)&pb16[off16];
            dst[0] = (uint)f2b(s0.x + s1.x) | ((uint)f2b(s0.y + s1.y) << 16);
            dst[1] = (uint)f2b(s0.z + s1.z) | ((uint)f2b(s0.w + s1.w) << 16);
        }
        if (tid < NH) { pbf[1008 + tid] = pm[tid]; pbf[1020 + tid] = ps[tid]; }
    }
}

// ---------------------------------------------------------------------------
// Kernel 3: combine 8 chunks -> cat16 row (bf16). grid 512, 256 threads.
// ---------------------------------------------------------------------------
__global__ __launch_bounds__(256) void k_combine(
    const uint* __restrict__ part, const float* __restrict__ rots,
    const float* __restrict__ trans, ushort* __restrict__ cat16)
{
    const int i   = blockIdx.x;
    const int tid = threadIdx.x;
    __shared__ float wgt[NCH][NH];
    __shared__ float ohp[288];

    const uint* base = part + (size_t)i * NCH * PSTRIDE32;
    if (tid < NH) {
        const int h = tid;
        float mm[NCH];
        float M = -1e30f;
        #pragma unroll
        for (int c = 0; c < NCH; ++c) {
            mm[c] = ((const float*)(base + c * PSTRIDE32))[1008 + h];
            M = fmaxf(M, mm[c]);
        }
        float S = 0.f;
        #pragma unroll
        for (int c = 0; c < NCH; ++c) {
            const float w = __expf(mm[c] - M);
            S += w * ((const float*)(base + c * PSTRIDE32))[1020 + h];
            wgt[c][h] = w;
        }
        const float inv = 1.0f / S;
        #pragma unroll
        for (int c = 0; c < NCH; ++c) wgt[c][h] *= inv;
    }
    __syncthreads();

    ushort* crow = cat16 + (size_t)i * 2112;
    uint*   crowu = (uint*)crow;
    if (tid < 192) {
        const int h = tid >> 4;
        float v[8];
        #pragma unroll
        for (int e = 0; e < 8; ++e) v[e] = 0.f;
        #pragma unroll
        for (int c = 0; c < NCH; ++c) {
            const uint4 u = *(const uint4*)&base[c * PSTRIDE32 + tid * 4];
            const float w = wgt[c][h];
            v[0] += b2f((ushort)u.x) * w; v[1] += b2f((ushort)(u.x >> 16)) * w;
            v[2] += b2f((ushort)u.y) * w; v[3] += b2f((ushort)(u.y >> 16)) * w;
            v[4] += b2f((ushort)u.z) * w; v[5] += b2f((ushort)(u.z >> 16)) * w;
            v[6] += b2f((ushort)u.w) * w; v[7] += b2f((ushort)(u.w >> 16)) * w;
        }
        uint4 o;
        o.x = (uint)f2b(v[0]) | ((uint)f2b(v[1]) << 16);
        o.y = (uint)f2b(v[2]) | ((uint)f2b(v[3]) << 16);
        o.z = (uint)f2b(v[4]) | ((uint)f2b(v[5]) << 16);
        o.w = (uint)f2b(v[6]) | ((uint)f2b(v[7]) << 16);
        *(uint4*)&crowu[tid * 4] = o;
    }
    if (tid < 96) {
        const int h = tid >> 3;
        float v0 = 0.f, v1 = 0.f;
        #pragma unroll
        for (int c = 0; c < NCH; ++c) {
            const uint u = base[c * PSTRIDE32 + 768 + tid];
            const float w = wgt[c][h];
            v0 += b2f((ushort)u) * w;
            v1 += b2f((ushort)(u >> 16)) * w;
        }
        crowu[768 + tid] = (uint)f2b(v0) | ((uint)f2b(v1) << 16);
    }
    if (tid < 144) {
        const int h = tid / 12;
        float v0 = 0.f, v1 = 0.f;
        #pragma unroll
        for (int c = 0; c < NCH; ++c) {
            const uint u = base[c * PSTRIDE32 + 864 + tid];
            const float w = wgt[c][h];
            v0 += b2f((ushort)u) * w;
            v1 += b2f((ushort)(u >> 16)) * w;
        }
        ohp[tid * 2] = v0; ohp[tid * 2 + 1] = v1;
    }
    __syncthreads();

    if (tid < 96) {
        const int h = tid >> 3, p = tid & 7;
        float R[9];
        #pragma unroll
        for (int k = 0; k < 9; ++k) R[k] = rots[(size_t)i * 9 + k];
        const float g0 = ohp[h * 24 + p * 3 + 0] - trans[(size_t)i * 3 + 0];
        const float g1 = ohp[h * 24 + p * 3 + 1] - trans[(size_t)i * 3 + 1];
        const float g2 = ohp[h * 24 + p * 3 + 2] - trans[(size_t)i * 3 + 2];
        const float oy0 = R[0] * g0 + R[3] * g1 + R[6] * g2;
        const float oy1 = R[1] * g0 + R[4] * g1 + R[7] * g2;
        const float oy2 = R[2] * g0 + R[5] * g1 + R[8] * g2;
        crow[1728 + h * 24 + p * 3 + 0] = f2b(oy0);
        crow[1728 + h * 24 + p * 3 + 1] = f2b(oy1);
        crow[1728 + h * 24 + p * 3 + 2] = f2b(oy2);
        crow[2016 + h * 8 + p] = f2b(sqrtf(oy0 * oy0 + oy1 * oy1 + oy2 * oy2));
    }
}

// ---------------------------------------------------------------------------
// Kernel 4: out-proj MFMA. grid (16 m, 12 n, 6 k). 4 waves = 2x2 16x16 tiles.
// ---------------------------------------------------------------------------
__global__ __launch_bounds__(256) void k_out(
    const ushort* __restrict__ cat16, const ushort* __restrict__ woT,
    float* __restrict__ opart)
{
    const int tid = threadIdx.x;
    const int wid = tid >> 6, lane = tid & 63;
    const int wm = wid >> 1, wn = wid & 1;
    const int i0 = blockIdx.x * 32 + wm * 16;
    const int c0 = blockIdx.y * 32 + wn * 16;
    const int k0 = blockIdx.z * 352;
    const ushort* arow = cat16 + (size_t)(i0 + (lane & 15)) * 2112 + k0 + (lane >> 4) * 8;
    const ushort* brow = woT   + (size_t)(c0 + (lane & 15)) * 2112 + k0 + (lane >> 4) * 8;
    floatx4 acc = {0.f, 0.f, 0.f, 0.f};
    #pragma unroll
    for (int st = 0; st < 11; ++st) {
        const short8v a = *(const short8v*)(arow + st * 32);
        const short8v b = *(const short8v*)(brow + st * 32);
        acc = __builtin_amdgcn_mfma_f32_16x16x32_bf16(a, b, acc, 0, 0, 0);
    }
    float* ob = opart + (size_t)blockIdx.z * 512 * 384;
    #pragma unroll
    for (int r = 0; r < 4; ++r) {
        const int i = i0 + (lane >> 4) * 4 + r;
        ob[(size_t)i * 384 + c0 + (lane & 15)] = acc[r];
    }
}

// Kernel 5: reduce 6 k-partials + bias.
__global__ __launch_bounds__(256) void k_outred(
    const float* __restrict__ opart, const float* __restrict__ bout,
    float* __restrict__ out)
{
    const int e4 = blockIdx.x * 256 + threadIdx.x;
    const float4* p = (const float4*)opart;
    const float4 b = ((const float4*)bout)[e4 % 96];
    float4 r = b;
    #pragma unroll
    for (int k = 0; k < KS; ++k) {
        const float4 v = p[e4 + k * 49152];
        r.x += v.x; r.y += v.y; r.z += v.z; r.w += v.w;
    }
    ((float4*)out)[e4] = r;
}

// ---------------------------------------------------------------------------
extern "C" void kernel_launch(void* const* d_in, const int* in_sizes, int n_in,
                              void* d_out, int out_size, void* d_ws, size_t ws_size,
                              hipStream_t stream)
{
    const float* s_i   = (const float*)d_in[0];
    const float* z_ij  = (const float*)d_in[1];
    const float* rots  = (const float*)d_in[2];
    const float* trans = (const float*)d_in[3];
    const float* Wq    = (const float*)d_in[4];
    const float* Wk    = (const float*)d_in[5];
    const float* Wv    = (const float*)d_in[6];
    const float* Wqp   = (const float*)d_in[7];
    const float* Wkp   = (const float*)d_in[8];
    const float* Wvp   = (const float*)d_in[9];
    const float* Wb    = (const float*)d_in[10];
    const float* gamma = (const float*)d_in[11];
    const float* Wout  = (const float*)d_in[12];
    const float* bout  = (const float*)d_in[13];
    float* ws = (float*)d_ws;
    float*  P     = ws;                          // 589824 f
    uint*   part  = (uint*)(P + 589824);         // 512*8*1040 u32 (17 MB)
    float*  opart = (float*)part;                // aliased (part consumed by
                                                 // k_combine before k_out writes)
    ushort* cat16 = (ushort*)(part + (size_t)512 * NCH * PSTRIDE32);  // 1081344 u16
    ushort* wbt16 = cat16 + 1081344;             // 2048 u16
    ushort* kfull = wbt16 + 2048;                // 512*352 u16
    ushort* woT   = kfull + 512 * KAW;           // 384*2112 u16
    ushort* vp2   = woT + (size_t)384 * 2112;    // 256*480*2 u16
    float*  out   = (float*)d_out;

    hipLaunchKernelGGL(k_gemm, dim3(24, 16), dim3(256), 0, stream,
                       s_i, Wq, Wk, Wv, Wqp, Wkp, Wvp, rots, trans, P);
    hipLaunchKernelGGL(k_aux, dim3(711), dim3(256), 0, stream,
                       P, Wb, Wout, kfull, vp2, wbt16, woT);
    hipLaunchKernelGGL(k_flash, dim3(512, NCH), dim3(256), 0, stream,
                       z_ij, wbt16, gamma, P, kfull, vp2, part);
    hipLaunchKernelGGL(k_combine, dim3(512), dim3(256), 0, stream,
                       part, rots, trans, cat16);
    hipLaunchKernelGGL(k_out, dim3(16, 12, KS), dim3(256), 0, stream,
                       cat16, woT, opart);
    hipLaunchKernelGGL(k_outred, dim3(192), dim3(256), 0, stream,
                       opart, bout, out);
}